// Round 1
// 633.095 us; speedup vs baseline: 1.0732x; 1.0732x over previous
//
#include <hip/hip_runtime.h>

typedef _Float16 f16x8 __attribute__((ext_vector_type(8)));
typedef _Float16 f16x4 __attribute__((ext_vector_type(4)));
typedef float f32x4 __attribute__((ext_vector_type(4)));

#define NA 512
#define NB 512
#define NV 32
#define ND 512
#define NBV (NB * NV)  // 16384

// ---- K0: prep. Per block b: VT[b][d][v] f16 (transposed), Vf[bv][d] f16,
//      and (blocks 0..255) Tf[a][d] f16. All reads/writes vectorized. ----
__global__ __launch_bounds__(256) void k_prep(const float* __restrict__ text,
                                              const float* __restrict__ video,
                                              _Float16* __restrict__ Tf,
                                              _Float16* __restrict__ Vf,
                                              _Float16* __restrict__ VT) {
  __shared__ _Float16 tile[ND * NV];  // 32 KB, [d][v]
  int b = blockIdx.x, t = threadIdx.x;
  const float* vb = video + (size_t)b * NV * ND;
  // transpose+convert into LDS
  int v = t >> 3, dc = (t & 7) * 64;
  for (int i = 0; i < 16; ++i) {
    f32x4 x = *(const f32x4*)(vb + v * ND + dc + i * 4);
    int d = dc + i * 4;
    tile[(d + 0) * NV + v] = (_Float16)x[0];
    tile[(d + 1) * NV + v] = (_Float16)x[1];
    tile[(d + 2) * NV + v] = (_Float16)x[2];
    tile[(d + 3) * NV + v] = (_Float16)x[3];
  }
  // flat f16 convert of video[b] (coalesced)
  for (int i = 0; i < 16; ++i) {
    int off = i * 1024 + t * 4;
    f32x4 x = *(const f32x4*)(vb + off);
    f16x4 h;
    h[0] = (_Float16)x[0]; h[1] = (_Float16)x[1];
    h[2] = (_Float16)x[2]; h[3] = (_Float16)x[3];
    *(f16x4*)(Vf + (size_t)b * (NV * ND) + off) = h;
  }
  // text convert (512*512 f32 = 256 blocks x 256 threads x f32x4)
  if (b < 256) {
    int idx = (b * 256 + t) * 4;
    f32x4 x = *(const f32x4*)(text + idx);
    f16x4 h;
    h[0] = (_Float16)x[0]; h[1] = (_Float16)x[1];
    h[2] = (_Float16)x[2]; h[3] = (_Float16)x[3];
    *(f16x4*)(Tf + idx) = h;
  }
  __syncthreads();
  f16x8* dst = (f16x8*)(VT + (size_t)b * ND * NV);
  const f16x8* src = (const f16x8*)tile;
  for (int i = 0; i < 8; ++i) dst[i * 256 + t] = src[i * 256 + t];
}

// XOR-swizzled LDS offset: row-major [row][32 f16], chunk = 8 f16.
__device__ inline int swz(int row, int ch) {
  return row * 32 + ((ch ^ ((row >> 1) & 3)) * 8);
}

// ---- K1: scores GEMM (f16 MFMA) + fused softmax over v -> W[a][b*32+v] f16
// M=512 (a), N=16384 (bv), K=512 (d). 64x128 tile, BK=32, 4 waves (2x2 of 32x64).
// Grid: (128, 8) = 1024 blocks -> 4 blocks/CU.
__global__ __launch_bounds__(256) void k_scores(const _Float16* __restrict__ Tf,
                                                const _Float16* __restrict__ Vf,
                                                _Float16* __restrict__ W) {
  __shared__ _Float16 As[64 * 32];   // 4 KB
  __shared__ _Float16 Bs[128 * 32];  // 8 KB
  int t = threadIdx.x;
  int m0 = blockIdx.y * 64, n0 = blockIdx.x * 128;
  int w = t >> 6, lane = t & 63, ln = lane & 15, q = lane >> 4;
  int wm = (w >> 1) * 32, wn = (w & 1) * 64;
  int ra = t >> 2, ca = t & 3;        // As staging: row 0..63, chunk 0..3
  int rb = t >> 1, cb = (t & 1) * 2;  // Bs staging: row 0..127, chunks cb,cb+1
  const _Float16* tA = Tf + (size_t)(m0 + ra) * ND + ca * 8;
  const _Float16* tB = Vf + (size_t)(n0 + rb) * ND + cb * 8;
  f32x4 acc[2][4];
  for (int i = 0; i < 2; ++i)
    for (int j = 0; j < 4; ++j) acc[i][j] = (f32x4){0.f, 0.f, 0.f, 0.f};

  for (int kk = 0; kk < 16; ++kk) {
    int k0 = kk * 32;
    __syncthreads();
    *(f16x8*)(As + swz(ra, ca)) = *(const f16x8*)(tA + k0);
    *(f16x8*)(Bs + swz(rb, cb)) = *(const f16x8*)(tB + k0);
    *(f16x8*)(Bs + swz(rb, cb + 1)) = *(const f16x8*)(tB + k0 + 8);
    __syncthreads();
    f16x8 af[2], bf[4];
    for (int mt = 0; mt < 2; ++mt)
      af[mt] = *(const f16x8*)(As + swz(wm + mt * 16 + ln, q));
    for (int nt = 0; nt < 4; ++nt)
      bf[nt] = *(const f16x8*)(Bs + swz(wn + nt * 16 + ln, q));
    for (int mt = 0; mt < 2; ++mt)
      for (int nt = 0; nt < 4; ++nt)
        acc[mt][nt] = __builtin_amdgcn_mfma_f32_16x16x32_f16(af[mt], bf[nt],
                                                             acc[mt][nt], 0, 0, 0);
  }

  // Softmax over each 32-col group (one b): cols g*32.. = n-tiles {2g, 2g+1}.
  // C/D layout: row(m) = q*4+r, col(n) = ln. Row-reduce across 16 lanes (same q).
  const float invT = 0.2f;  // 1/TEMP
  for (int mt = 0; mt < 2; ++mt) {
    for (int g = 0; g < 2; ++g) {
      for (int r = 0; r < 4; ++r) {
        float v0 = acc[mt][2 * g][r] * invT;
        float v1 = acc[mt][2 * g + 1][r] * invT;
        float mx = fmaxf(v0, v1);
        for (int msk = 1; msk < 16; msk <<= 1)
          mx = fmaxf(mx, __shfl_xor(mx, msk, 16));
        float p0 = __expf(v0 - mx), p1 = __expf(v1 - mx);
        float s = p0 + p1;
        for (int msk = 1; msk < 16; msk <<= 1)
          s += __shfl_xor(s, msk, 16);
        float inv = 1.0f / s;
        int a = m0 + wm + mt * 16 + q * 4 + r;
        int col = n0 + wn + g * 32 + ln;
        W[(size_t)a * NBV + col] = (_Float16)(p0 * inv);
        W[(size_t)a * NBV + col + 16] = (_Float16)(p1 * inv);
      }
    }
  }
}

// ---- K2: out[a][b][d] = sum_v W[a][b*32+v] * VT[b][d][v]; K=32 -> 1 MFMA/tile
// Swapped operands: A = VT rows (m=d), B = W rows (n=a)  =>  D col=a, row=d,
// so c[0..3] is contiguous in d -> f32x4 stores.
// Block: 64 a x 8 b x all 512 d; 8 waves, wave w owns d in [w*64, w*64+64).
// No LDS, no barriers: VT frag loads are 1KB-coalesced from global.
__global__ __launch_bounds__(512) void k_pool(const _Float16* __restrict__ W,
                                              const _Float16* __restrict__ VT,
                                              float* __restrict__ out) {
  int t = threadIdx.x;
  int w = t >> 6, lane = t & 63, ln = lane & 15, q = lane >> 4;
  int b0 = blockIdx.x * 8, a0 = blockIdx.y * 64;
  int d0 = w * 64;
  const _Float16* Wbase = W + (size_t)(a0 + ln) * NBV + b0 * NV + q * 8;
  for (int ib = 0; ib < 8; ++ib) {
    const _Float16* vtb =
        VT + ((size_t)(b0 + ib) * ND + d0 + ln) * NV + q * 8;
    f16x8 wf[4], vf[4];
    for (int nt = 0; nt < 4; ++nt)
      wf[nt] = *(const f16x8*)(Wbase + (size_t)nt * 16 * NBV + ib * NV);
    for (int mt = 0; mt < 4; ++mt)
      vf[mt] = *(const f16x8*)(vtb + mt * 16 * NV);
    for (int nt = 0; nt < 4; ++nt) {
      for (int mt = 0; mt < 4; ++mt) {
        f32x4 c = (f32x4){0.f, 0.f, 0.f, 0.f};
        c = __builtin_amdgcn_mfma_f32_16x16x32_f16(vf[mt], wf[nt], c, 0, 0, 0);
        float* dst = out + ((size_t)(a0 + nt * 16 + ln) * NB + b0 + ib) * ND +
                     d0 + mt * 16 + q * 4;
        *(f32x4*)dst = c;
      }
    }
  }
}

extern "C" void kernel_launch(void* const* d_in, const int* in_sizes, int n_in,
                              void* d_out, int out_size, void* d_ws, size_t ws_size,
                              hipStream_t stream) {
  const float* text = (const float*)d_in[0];
  const float* video = (const float*)d_in[1];
  float* out = (float*)d_out;
  // workspace (f16): VT 16MB | W 16MB | Vf 16MB | Tf 0.5MB  = 48.5 MB
  _Float16* ws = (_Float16*)d_ws;
  _Float16* VT = ws;
  _Float16* W  = ws + (size_t)8 * 1024 * 1024;
  _Float16* Vf = ws + (size_t)16 * 1024 * 1024;
  _Float16* Tf = ws + (size_t)24 * 1024 * 1024;
  k_prep<<<dim3(NB), 256, 0, stream>>>(text, video, Tf, Vf, VT);
  k_scores<<<dim3(NBV / 128, NA / 64), 256, 0, stream>>>(Tf, Vf, W);
  k_pool<<<dim3(NB / 8, NA / 64), 512, 0, stream>>>(W, VT, out);
}